// Round 4
// baseline (714.438 us; speedup 1.0000x reference)
//
#include <hip/hip_runtime.h>
#include <hip/hip_bf16.h>

#define N_NODES 10000
#define E_EDGES 160000

typedef __attribute__((ext_vector_type(8))) short bf16x8;
typedef __attribute__((ext_vector_type(4))) float f32x4;

__device__ __forceinline__ unsigned short f2b(float f) {
    unsigned int u = __float_as_uint(f);
    u = (u + 0x7fffu + ((u >> 16) & 1u)) >> 16;
    return (unsigned short)u;
}

__device__ __forceinline__ float b2f(unsigned short u) {
    return __uint_as_float(((unsigned int)u) << 16);
}

__device__ __forceinline__ float tanh_fast(float x) {
    float ax = fabsf(x);
    float e = __expf(-2.f * ax);
    float r = (1.f - e) / (1.f + e);
    return copysignf(r, x);
}

// ---------------- small GCN-prep kernels ----------------
__global__ void init_kernel(float* deg, int* cnt) {
    int i = blockIdx.x * 256 + threadIdx.x;
    if (i < N_NODES) { deg[i] = 1.0f; cnt[i] = 0; }   // 1.0 = self-loop weight
}

__global__ void deg_add_kernel(const int* __restrict__ ei, const float* __restrict__ ew,
                               float* deg, int* cnt) {
    int e = blockIdx.x * 256 + threadIdx.x;
    if (e < E_EDGES) {
        int c = ei[E_EDGES + e];
        atomicAdd(&deg[c], ew[e]);
        atomicAdd(&cnt[c], 1);
    }
}

__global__ void dinv_kernel(const float* __restrict__ deg, float* dinv) {
    int i = blockIdx.x * 256 + threadIdx.x;
    if (i < N_NODES) { float d = deg[i]; dinv[i] = d > 0.f ? rsqrtf(d) : 0.f; }
}

// exclusive prefix sum of cnt[N] -> offs[N+1], cursor[N]
__global__ void scan_kernel(const int* __restrict__ cnt, int* offs, int* cursor) {
    __shared__ int tsum[1024];
    int t = threadIdx.x;
    int base = t * 10;
    int loc[10];
    int s = 0;
    #pragma unroll
    for (int j = 0; j < 10; ++j) {
        int i = base + j;
        int v = (i < N_NODES) ? cnt[i] : 0;
        loc[j] = s; s += v;
    }
    tsum[t] = s;
    __syncthreads();
    for (int d = 1; d < 1024; d <<= 1) {
        int v = (t >= d) ? tsum[t - d] : 0;
        __syncthreads();
        tsum[t] += v;
        __syncthreads();
    }
    int pre = tsum[t] - s;   // exclusive
    #pragma unroll
    for (int j = 0; j < 10; ++j) {
        int i = base + j;
        if (i < N_NODES) { offs[i] = pre + loc[j]; cursor[i] = pre + loc[j]; }
    }
    if (t == 1023) offs[N_NODES] = tsum[1023];
}

__global__ void fill_kernel(const int* __restrict__ ei, const float* __restrict__ ew,
                            const float* __restrict__ dinv, int* cursor,
                            int* erow, float* enorm) {
    int e = blockIdx.x * 256 + threadIdx.x;
    if (e < E_EDGES) {
        int r = ei[e], c = ei[E_EDGES + e];
        float nm = dinv[r] * ew[e] * dinv[c];
        int pos = atomicAdd(&cursor[c], 1);
        erow[pos] = r; enorm[pos] = nm;
    }
}

// -------------- CSR gather-aggregate: one wave per target node ----------------
// xlt layout: [N][G=16][64] f32. gc layout: [G][N][64] bf16 (== seq flat rows)
__global__ __launch_bounds__(256) void aggregate_kernel(
        const float* __restrict__ xlt, const int* __restrict__ erow,
        const float* __restrict__ enorm, const int* __restrict__ offs,
        const float* __restrict__ dinv, const float* __restrict__ gcn_b,
        unsigned short* __restrict__ gc) {
    int c = (blockIdx.x * 256 + threadIdx.x) >> 6;
    int lane = threadIdx.x & 63;
    if (c >= N_NODES) return;
    float acc[16];
    float d = dinv[c];
    float wself = d * d;
    const float* xr = xlt + (long)c * 1024;
    #pragma unroll
    for (int g = 0; g < 16; ++g) acc[g] = xr[g * 64 + lane] * wself;
    int e0 = offs[c], e1 = offs[c + 1];
    for (int e = e0; e < e1; ++e) {
        int r = erow[e];
        float nm = enorm[e];
        const float* xs = xlt + (long)r * 1024;
        #pragma unroll
        for (int g = 0; g < 16; ++g) acc[g] += xs[g * 64 + lane] * nm;
    }
    float bb = gcn_b[lane];
    #pragma unroll
    for (int g = 0; g < 16; ++g)
        gc[(long)g * 640000 + (long)c * 64 + lane] = f2b(acc[g] + bb);
}

// -------------- generic bf16-MFMA GEMM: C[m,n] = A[m,:K] . W[n,:K] + bias ----------------
// BM=128, BK=64, 4 waves (2x2). EPI: 0=xlt scatter f32, 1=plain f32, 2=bf16(+relu), 3=final strided f32
template<int NTOT, int BN, int KTOT, bool AF32, int EPI, bool RELU>
__global__ __launch_bounds__(256) void gemm_kernel(
        const void* __restrict__ Aptr, const float* __restrict__ Wp,
        const float* __restrict__ bias0, const float* __restrict__ bias1,
        void* __restrict__ outp) {
    constexpr int WN = BN / 2;
    constexpr int FN = WN / 16;
    __shared__ __align__(16) unsigned short As[128 * 72];
    __shared__ __align__(16) unsigned short Bs[BN * 72];
    const int tid = threadIdx.x;
    const int lane = tid & 63;
    const int wid = tid >> 6;
    const int wm = wid >> 1, wn = wid & 1;
    const long m0 = (long)blockIdx.x * 128;
    const int n0 = blockIdx.y * BN;

    f32x4 acc[4][FN];
    #pragma unroll
    for (int a = 0; a < 4; ++a)
        #pragma unroll
        for (int b = 0; b < FN; ++b)
            acc[a][b] = (f32x4){0.f, 0.f, 0.f, 0.f};

    for (int kt = 0; kt < KTOT / 64; ++kt) {
        if (AF32) {
            const float* Ag = (const float*)Aptr;
            #pragma unroll
            for (int p = 0; p < 8; ++p) {
                int idx = p * 256 + tid;
                int r = idx >> 4, c4 = idx & 15;
                float4 v = *(const float4*)(Ag + (m0 + r) * KTOT + kt * 64 + c4 * 4);
                ushort4 h; h.x = f2b(v.x); h.y = f2b(v.y); h.z = f2b(v.z); h.w = f2b(v.w);
                *(ushort4*)&As[r * 72 + c4 * 4] = h;
            }
        } else {
            const unsigned short* Ag = (const unsigned short*)Aptr;
            #pragma unroll
            for (int p = 0; p < 4; ++p) {
                int idx = p * 256 + tid;
                int r = idx >> 3, c8 = idx & 7;
                *(int4*)&As[r * 72 + c8 * 8] = *(const int4*)(Ag + (m0 + r) * KTOT + kt * 64 + c8 * 8);
            }
        }
        #pragma unroll
        for (int p = 0; p < BN / 16; ++p) {
            int idx = p * 256 + tid;
            int r = idx >> 4, c4 = idx & 15;
            float4 v = *(const float4*)(Wp + (long)(n0 + r) * KTOT + kt * 64 + c4 * 4);
            ushort4 h; h.x = f2b(v.x); h.y = f2b(v.y); h.z = f2b(v.z); h.w = f2b(v.w);
            *(ushort4*)&Bs[r * 72 + c4 * 4] = h;
        }
        __syncthreads();
        #pragma unroll
        for (int ks = 0; ks < 2; ++ks) {
            bf16x8 a[4], b[FN];
            #pragma unroll
            for (int fm = 0; fm < 4; ++fm)
                a[fm] = *(const bf16x8*)&As[(wm * 64 + fm * 16 + (lane & 15)) * 72 + ks * 32 + (lane >> 4) * 8];
            #pragma unroll
            for (int fn = 0; fn < FN; ++fn)
                b[fn] = *(const bf16x8*)&Bs[(wn * WN + fn * 16 + (lane & 15)) * 72 + ks * 32 + (lane >> 4) * 8];
            #pragma unroll
            for (int fm = 0; fm < 4; ++fm)
                #pragma unroll
                for (int fn = 0; fn < FN; ++fn)
                    acc[fm][fn] = __builtin_amdgcn_mfma_f32_16x16x32_bf16(a[fm], b[fn], acc[fm][fn], 0, 0, 0);
        }
        __syncthreads();
    }

    #pragma unroll
    for (int fm = 0; fm < 4; ++fm) {
        #pragma unroll
        for (int fn = 0; fn < FN; ++fn) {
            const int colg = n0 + wn * WN + fn * 16 + (lane & 15);
            float bv = 0.f;
            if (bias0) bv += bias0[colg];
            if (bias1) bv += bias1[colg];
            #pragma unroll
            for (int r = 0; r < 4; ++r) {
                int row = (int)m0 + wm * 64 + fm * 16 + (lane >> 4) * 4 + r;
                float v = acc[fm][fn][r] + bv;
                if (RELU) v = fmaxf(v, 0.f);
                if (EPI == 0) {
                    ((float*)outp)[(long)(row % N_NODES) * 1024 + (long)(row / N_NODES) * 64 + colg] = v;
                } else if (EPI == 1) {
                    ((float*)outp)[(long)row * NTOT + colg] = v;
                } else if (EPI == 2) {
                    ((unsigned short*)outp)[(long)row * NTOT + colg] = f2b(v);
                } else {
                    ((float*)outp)[((long)(row >> 3) * 10 + (row & 7)) * 64 + colg] = v;
                }
            }
        }
    }
}

// -------------- RNN recurrence: 80 rows/block, 8 steps, w_hh stationary in LDS ----------------
__global__ __launch_bounds__(256) void rnn_kernel(const unsigned short* __restrict__ xih,
                                                  const float* __restrict__ whh,
                                                  unsigned short* __restrict__ rout) {
    __shared__ __align__(16) unsigned short hs[80 * 128];
    __shared__ __align__(16) unsigned short ws[128 * 128];
    const int tid = threadIdx.x, lane = tid & 63, wid = tid >> 6;  // 4 waves: col split of 32
    const long i0 = (long)blockIdx.x * 80;

    // stage w_hh -> bf16, XOR-swizzled rows (byte ^= (row&7)<<4)
    #pragma unroll
    for (int p = 0; p < 16; ++p) {
        int idx = p * 256 + tid;
        int n = idx >> 5, k4 = (idx & 31) * 4;
        float4 v = *(const float4*)(whh + n * 128 + k4);
        ushort4 h; h.x = f2b(v.x); h.y = f2b(v.y); h.z = f2b(v.z); h.w = f2b(v.w);
        int byte = (n * 256 + k4 * 2) ^ ((n & 7) << 4);
        *(ushort4*)((char*)ws + byte) = h;
    }
    int4 z = make_int4(0, 0, 0, 0);
    #pragma unroll
    for (int p = 0; p < 5; ++p) ((int4*)hs)[p * 256 + tid] = z;   // 80*128*2B = 1280 int4
    __syncthreads();

    f32x4 acc[5][2];
    for (int t = 0; t < 8; ++t) {
        #pragma unroll
        for (int fm = 0; fm < 5; ++fm)
            #pragma unroll
            for (int fn = 0; fn < 2; ++fn) {
                int col = wid * 32 + fn * 16 + (lane & 15);
                int rbase = fm * 16 + (lane >> 4) * 4;
                const unsigned short* src = xih + ((i0 + rbase) * 8 + t) * 128 + col;
                #pragma unroll
                for (int r = 0; r < 4; ++r) acc[fm][fn][r] = b2f(src[(long)r * 1024]);
            }
        #pragma unroll
        for (int ks = 0; ks < 4; ++ks) {
            bf16x8 a[5], b[2];
            #pragma unroll
            for (int fm = 0; fm < 5; ++fm) {
                int row = fm * 16 + (lane & 15);
                int byte = (row * 256 + ks * 64 + (lane >> 4) * 16) ^ ((row & 7) << 4);
                a[fm] = *(const bf16x8*)((const char*)hs + byte);
            }
            #pragma unroll
            for (int fn = 0; fn < 2; ++fn) {
                int rowb = wid * 32 + fn * 16 + (lane & 15);
                int byte = (rowb * 256 + ks * 64 + (lane >> 4) * 16) ^ ((rowb & 7) << 4);
                b[fn] = *(const bf16x8*)((const char*)ws + byte);
            }
            #pragma unroll
            for (int fm = 0; fm < 5; ++fm)
                #pragma unroll
                for (int fn = 0; fn < 2; ++fn)
                    acc[fm][fn] = __builtin_amdgcn_mfma_f32_16x16x32_bf16(a[fm], b[fn], acc[fm][fn], 0, 0, 0);
        }
        __syncthreads();   // all reads of h_{t-1} done
        #pragma unroll
        for (int fm = 0; fm < 5; ++fm)
            #pragma unroll
            for (int fn = 0; fn < 2; ++fn) {
                int col = wid * 32 + fn * 16 + (lane & 15);
                #pragma unroll
                for (int r = 0; r < 4; ++r) {
                    int row = fm * 16 + (lane >> 4) * 4 + r;
                    float v = tanh_fast(acc[fm][fn][r]);
                    unsigned short hb = f2b(v);
                    int byte = (row * 256 + col * 2) ^ ((row & 7) << 4);
                    *(unsigned short*)((char*)hs + byte) = hb;
                    rout[((i0 + row) * 8 + t) * 128 + col] = hb;
                }
            }
        __syncthreads();   // h_t fully written
    }
}

extern "C" void kernel_launch(void* const* d_in, const int* in_sizes, int n_in,
                              void* d_out, int out_size, void* d_ws, size_t ws_size,
                              hipStream_t stream) {
    const float* x     = (const float*)d_in[0];
    const int*   ei    = (const int*)  d_in[1];
    const float* ew    = (const float*)d_in[2];
    const float* gcn_w = (const float*)d_in[3];
    const float* gcn_b = (const float*)d_in[4];
    const float* w_ih  = (const float*)d_in[5];
    const float* w_hh  = (const float*)d_in[6];
    const float* b_ih  = (const float*)d_in[7];
    const float* b_hh  = (const float*)d_in[8];
    const float* w1    = (const float*)d_in[9];
    const float* b1    = (const float*)d_in[10];
    const float* w2    = (const float*)d_in[11];
    const float* b2    = (const float*)d_in[12];
    const float* w3    = (const float*)d_in[13];
    const float* b3    = (const float*)d_in[14];

    // ---- workspace layout (peak ~122 MiB) ----
    // [0, 41.0M):       xlt f32 [N][16][64]      -> dead after aggregate; then rnno bf16 [160000][128]
    // [41.94M, 62.42M): gc  bf16 [160000][64]    -> dead after GEMM-ih
    // [62.91M,103.87M): xih bf16 [160000][128]   -> dead after RNN
    // [41.94M, 83.89M): y1 bf16 chunk [40960][512]  (over gc + xih head, both dead)
    // [83.89M,125.83M): y2 bf16 chunk [40960][512]  (over xih tail, dead)
    // [125.83M, ...):   small graph buffers (~1.7 MB)
    char* ws = (char*)d_ws;
    float*          xlt  = (float*)ws;
    unsigned short* rnno = (unsigned short*)ws;
    unsigned short* gc   = (unsigned short*)(ws + 41943040L);
    unsigned short* xih  = (unsigned short*)(ws + 62914560L);
    unsigned short* y1b  = (unsigned short*)(ws + 41943040L);
    unsigned short* y2b  = (unsigned short*)(ws + 83886080L);
    char* sm = ws + 125829120L;
    float* deg    = (float*)(sm);
    float* dinv   = (float*)(sm + (64 << 10));
    int*   cnt    = (int*)  (sm + (128 << 10));
    int*   offs   = (int*)  (sm + (192 << 10));
    int*   cursor = (int*)  (sm + (256 << 10));
    int*   erow   = (int*)  (sm + (320 << 10));           // 640 KB
    float* enorm  = (float*)(sm + (1 << 20));             // 640 KB

    hipMemsetAsync(d_out, 0, (size_t)out_size * sizeof(float), stream);  // prediction slots stay 0

    init_kernel<<<40, 256, 0, stream>>>(deg, cnt);
    deg_add_kernel<<<625, 256, 0, stream>>>(ei, ew, deg, cnt);
    dinv_kernel<<<40, 256, 0, stream>>>(deg, dinv);
    scan_kernel<<<1, 1024, 0, stream>>>(cnt, offs, cursor);
    fill_kernel<<<625, 256, 0, stream>>>(ei, ew, dinv, cursor, erow, enorm);

    // xl^T[n][g][f] = x[g,n,:] . gcn_w[f,:]   (fp32 in, bf16 MFMA, f32 out, no bias)
    gemm_kernel<64, 64, 64, true, 0, false><<<dim3(1250, 1), 256, 0, stream>>>(x, gcn_w, nullptr, nullptr, xlt);
    aggregate_kernel<<<2500, 256, 0, stream>>>(xlt, erow, enorm, offs, dinv, gcn_b, gc);
    // xih[v][h] = gc[v,:] . w_ih[h,:] + b_ih + b_hh  (bf16 out)
    gemm_kernel<128, 128, 64, false, 2, false><<<dim3(1250, 1), 256, 0, stream>>>(gc, w_ih, b_ih, b_hh, xih);
    rnn_kernel<<<250, 256, 0, stream>>>(xih, w_hh, rnno);

    // MLP in 4 M-chunks of 40960 rows (last: 37120), reusing 42MB y buffers
    const long CH = 40960;
    for (int c = 0; c < 4; ++c) {
        long r0 = c * CH;
        long nr = (c == 3) ? (160000L - 3 * CH) : CH;
        int nb = (int)(nr / 128);
        gemm_kernel<512, 128, 128, false, 2, true ><<<dim3(nb, 4), 256, 0, stream>>>(rnno + r0 * 128, w1, b1, nullptr, y1b);
        gemm_kernel<512, 128, 512, false, 2, true ><<<dim3(nb, 4), 256, 0, stream>>>(y1b, w2, b2, nullptr, y2b);
        gemm_kernel<64, 64, 512, false, 3, false><<<dim3(nb, 1), 256, 0, stream>>>(y2b, w3, b3, nullptr, (float*)d_out + (r0 / 8) * 640);
    }
}

// Round 5
// 452.300 us; speedup vs baseline: 1.5796x; 1.5796x over previous
//
#include <hip/hip_runtime.h>
#include <hip/hip_bf16.h>

#define N_NODES 10000
#define E_EDGES 160000

typedef __attribute__((ext_vector_type(8))) short bf16x8;
typedef __attribute__((ext_vector_type(4))) float f32x4;

__device__ __forceinline__ unsigned short f2b(float f) {
    unsigned int u = __float_as_uint(f);
    u = (u + 0x7fffu + ((u >> 16) & 1u)) >> 16;
    return (unsigned short)u;
}

__device__ __forceinline__ float b2f(unsigned short u) {
    return __uint_as_float(((unsigned int)u) << 16);
}

__device__ __forceinline__ float tanh_fast(float x) {
    float ax = fabsf(x);
    float e = __expf(-2.f * ax);
    float r = (1.f - e) / (1.f + e);
    return copysignf(r, x);
}

// ---------------- small GCN-prep kernels ----------------
__global__ void init_kernel(float* deg, int* cnt) {
    int i = blockIdx.x * 256 + threadIdx.x;
    if (i < N_NODES) { deg[i] = 1.0f; cnt[i] = 0; }   // 1.0 = self-loop weight
}

__global__ void deg_add_kernel(const int* __restrict__ ei, const float* __restrict__ ew,
                               float* deg, int* cnt) {
    int e = blockIdx.x * 256 + threadIdx.x;
    if (e < E_EDGES) {
        int c = ei[E_EDGES + e];
        atomicAdd(&deg[c], ew[e]);
        atomicAdd(&cnt[c], 1);
    }
}

__global__ void dinv_kernel(const float* __restrict__ deg, float* dinv) {
    int i = blockIdx.x * 256 + threadIdx.x;
    if (i < N_NODES) { float d = deg[i]; dinv[i] = d > 0.f ? rsqrtf(d) : 0.f; }
}

// exclusive prefix sum of cnt[N] -> offs[N+1], cursor[N]
__global__ void scan_kernel(const int* __restrict__ cnt, int* offs, int* cursor) {
    __shared__ int tsum[1024];
    int t = threadIdx.x;
    int base = t * 10;
    int loc[10];
    int s = 0;
    #pragma unroll
    for (int j = 0; j < 10; ++j) {
        int i = base + j;
        int v = (i < N_NODES) ? cnt[i] : 0;
        loc[j] = s; s += v;
    }
    tsum[t] = s;
    __syncthreads();
    for (int d = 1; d < 1024; d <<= 1) {
        int v = (t >= d) ? tsum[t - d] : 0;
        __syncthreads();
        tsum[t] += v;
        __syncthreads();
    }
    int pre = tsum[t] - s;   // exclusive
    #pragma unroll
    for (int j = 0; j < 10; ++j) {
        int i = base + j;
        if (i < N_NODES) { offs[i] = pre + loc[j]; cursor[i] = pre + loc[j]; }
    }
    if (t == 1023) offs[N_NODES] = tsum[1023];
}

__global__ void fill_kernel(const int* __restrict__ ei, const float* __restrict__ ew,
                            const float* __restrict__ dinv, int* cursor,
                            int* erow, float* enorm) {
    int e = blockIdx.x * 256 + threadIdx.x;
    if (e < E_EDGES) {
        int r = ei[e], c = ei[E_EDGES + e];
        float nm = dinv[r] * ew[e] * dinv[c];
        int pos = atomicAdd(&cursor[c], 1);
        erow[pos] = r; enorm[pos] = nm;
    }
}

// ---- weight -> bf16 MFMA-fragment-major layout: frag(nf,ks) = 1KB, lane-major ----
template<int KS, int K>
__global__ void wconv_kernel(const float* __restrict__ w, unsigned short* __restrict__ o) {
    int idx = blockIdx.x * 256 + threadIdx.x;   // frag*64 + lane
    int lane = idx & 63, frag = idx >> 6;
    int nf = frag / KS, ks = frag % KS;
    const float* src = w + (nf * 16 + (lane & 15)) * K + ks * 32 + (lane >> 4) * 8;
    unsigned short* dst = o + frag * 512 + lane * 8;
    float4 v0 = *(const float4*)src;
    float4 v1 = *(const float4*)(src + 4);
    ushort4 h0; h0.x = f2b(v0.x); h0.y = f2b(v0.y); h0.z = f2b(v0.z); h0.w = f2b(v0.w);
    ushort4 h1; h1.x = f2b(v1.x); h1.y = f2b(v1.y); h1.z = f2b(v1.z); h1.w = f2b(v1.w);
    *(ushort4*)dst = h0;
    *(ushort4*)(dst + 4) = h1;
}

// -------------- CSR gather-aggregate: 2 waves per target node (8 graphs each) ----------------
// xlt layout: [N][G=16][64] bf16. gc layout: [G][N][64] bf16 (== seq flat rows)
__global__ __launch_bounds__(256) void aggregate_kernel(
        const unsigned short* __restrict__ xlt, const int* __restrict__ erow,
        const float* __restrict__ enorm, const int* __restrict__ offs,
        const float* __restrict__ dinv, const float* __restrict__ gcn_b,
        unsigned short* __restrict__ gc) {
    int gwid = (blockIdx.x * 256 + threadIdx.x) >> 6;   // 20000 waves
    int c = gwid >> 1;
    int gh = (gwid & 1) * 8;
    int lane = threadIdx.x & 63;
    if (c >= N_NODES) return;
    float acc[8];
    float d = dinv[c];
    float wself = d * d;
    const unsigned short* xr = xlt + (long)c * 1024 + gh * 64;
    #pragma unroll
    for (int g = 0; g < 8; ++g) acc[g] = b2f(xr[g * 64 + lane]) * wself;
    int e0 = offs[c], e1 = offs[c + 1];
    for (int e = e0; e < e1; ++e) {
        int r = erow[e];
        float nm = enorm[e];
        const unsigned short* xs = xlt + (long)r * 1024 + gh * 64;
        #pragma unroll
        for (int g = 0; g < 8; ++g) acc[g] += b2f(xs[g * 64 + lane]) * nm;
    }
    float bb = gcn_b[lane];
    #pragma unroll
    for (int g = 0; g < 8; ++g)
        gc[(long)(gh + g) * 640000 + (long)c * 64 + lane] = f2b(acc[g] + bb);
}

// -------------- generic bf16-MFMA GEMM: C[m,n] = A[m,:K] . W[n,:K] + bias ----------------
// BM=128, BK=64, 4 waves (2x2). EPI: 0=xlt scatter bf16, 2=bf16(+relu)
template<int NTOT, int BN, int KTOT, bool AF32, int EPI, bool RELU>
__global__ __launch_bounds__(256) void gemm_kernel(
        const void* __restrict__ Aptr, const float* __restrict__ Wp,
        const float* __restrict__ bias0, const float* __restrict__ bias1,
        void* __restrict__ outp) {
    constexpr int WN = BN / 2;
    constexpr int FN = WN / 16;
    __shared__ __align__(16) unsigned short As[128 * 72];
    __shared__ __align__(16) unsigned short Bs[BN * 72];
    const int tid = threadIdx.x;
    const int lane = tid & 63;
    const int wid = tid >> 6;
    const int wm = wid >> 1, wn = wid & 1;
    const long m0 = (long)blockIdx.x * 128;
    const int n0 = blockIdx.y * BN;

    f32x4 acc[4][FN];
    #pragma unroll
    for (int a = 0; a < 4; ++a)
        #pragma unroll
        for (int b = 0; b < FN; ++b)
            acc[a][b] = (f32x4){0.f, 0.f, 0.f, 0.f};

    for (int kt = 0; kt < KTOT / 64; ++kt) {
        if (AF32) {
            const float* Ag = (const float*)Aptr;
            #pragma unroll
            for (int p = 0; p < 8; ++p) {
                int idx = p * 256 + tid;
                int r = idx >> 4, c4 = idx & 15;
                float4 v = *(const float4*)(Ag + (m0 + r) * KTOT + kt * 64 + c4 * 4);
                ushort4 h; h.x = f2b(v.x); h.y = f2b(v.y); h.z = f2b(v.z); h.w = f2b(v.w);
                *(ushort4*)&As[r * 72 + c4 * 4] = h;
            }
        } else {
            const unsigned short* Ag = (const unsigned short*)Aptr;
            #pragma unroll
            for (int p = 0; p < 4; ++p) {
                int idx = p * 256 + tid;
                int r = idx >> 3, c8 = idx & 7;
                *(int4*)&As[r * 72 + c8 * 8] = *(const int4*)(Ag + (m0 + r) * KTOT + kt * 64 + c8 * 8);
            }
        }
        #pragma unroll
        for (int p = 0; p < BN / 16; ++p) {
            int idx = p * 256 + tid;
            int r = idx >> 4, c4 = idx & 15;
            float4 v = *(const float4*)(Wp + (long)(n0 + r) * KTOT + kt * 64 + c4 * 4);
            ushort4 h; h.x = f2b(v.x); h.y = f2b(v.y); h.z = f2b(v.z); h.w = f2b(v.w);
            *(ushort4*)&Bs[r * 72 + c4 * 4] = h;
        }
        __syncthreads();
        #pragma unroll
        for (int ks = 0; ks < 2; ++ks) {
            bf16x8 a[4], b[FN];
            #pragma unroll
            for (int fm = 0; fm < 4; ++fm)
                a[fm] = *(const bf16x8*)&As[(wm * 64 + fm * 16 + (lane & 15)) * 72 + ks * 32 + (lane >> 4) * 8];
            #pragma unroll
            for (int fn = 0; fn < FN; ++fn)
                b[fn] = *(const bf16x8*)&Bs[(wn * WN + fn * 16 + (lane & 15)) * 72 + ks * 32 + (lane >> 4) * 8];
            #pragma unroll
            for (int fm = 0; fm < 4; ++fm)
                #pragma unroll
                for (int fn = 0; fn < FN; ++fn)
                    acc[fm][fn] = __builtin_amdgcn_mfma_f32_16x16x32_bf16(a[fm], b[fn], acc[fm][fn], 0, 0, 0);
        }
        __syncthreads();
    }

    #pragma unroll
    for (int fm = 0; fm < 4; ++fm) {
        #pragma unroll
        for (int fn = 0; fn < FN; ++fn) {
            const int colg = n0 + wn * WN + fn * 16 + (lane & 15);
            float bv = 0.f;
            if (bias0) bv += bias0[colg];
            if (bias1) bv += bias1[colg];
            #pragma unroll
            for (int r = 0; r < 4; ++r) {
                int row = (int)m0 + wm * 64 + fm * 16 + (lane >> 4) * 4 + r;
                float v = acc[fm][fn][r] + bv;
                if (RELU) v = fmaxf(v, 0.f);
                if (EPI == 0) {
                    ((unsigned short*)outp)[(long)(row % N_NODES) * 1024 + (long)(row / N_NODES) * 64 + colg] = f2b(v);
                } else {
                    ((unsigned short*)outp)[(long)row * NTOT + colg] = f2b(v);
                }
            }
        }
    }
}

// -------------- RNN recurrence: 80 rows/block, 8 steps, w_hh stationary in LDS ----------------
// xih prefetch ping-pong (t fully unrolled -> static indexing)
__global__ __launch_bounds__(256) void rnn_kernel(const unsigned short* __restrict__ xih,
                                                  const float* __restrict__ whh,
                                                  unsigned short* __restrict__ rout) {
    __shared__ __align__(16) unsigned short hs[80 * 128];
    __shared__ __align__(16) unsigned short ws[128 * 128];
    const int tid = threadIdx.x, lane = tid & 63, wid = tid >> 6;  // 4 waves: col split of 32
    const long i0 = (long)blockIdx.x * 80;

    // stage w_hh -> bf16, XOR-swizzled rows (byte ^= (row&7)<<4)
    #pragma unroll
    for (int p = 0; p < 16; ++p) {
        int idx = p * 256 + tid;
        int n = idx >> 5, k4 = (idx & 31) * 4;
        float4 v = *(const float4*)(whh + n * 128 + k4);
        ushort4 h; h.x = f2b(v.x); h.y = f2b(v.y); h.z = f2b(v.z); h.w = f2b(v.w);
        int byte = (n * 256 + k4 * 2) ^ ((n & 7) << 4);
        *(ushort4*)((char*)ws + byte) = h;
    }
    int4 z = make_int4(0, 0, 0, 0);
    #pragma unroll
    for (int p = 0; p < 5; ++p) ((int4*)hs)[p * 256 + tid] = z;
    __syncthreads();

    unsigned short x2[2][5][2][4];
    // preload t=0
    #pragma unroll
    for (int fm = 0; fm < 5; ++fm)
        #pragma unroll
        for (int fn = 0; fn < 2; ++fn) {
            int col = wid * 32 + fn * 16 + (lane & 15);
            const unsigned short* src = xih + ((i0 + fm * 16 + (lane >> 4) * 4) * 8 + 0) * 128 + col;
            #pragma unroll
            for (int r = 0; r < 4; ++r) x2[0][fm][fn][r] = src[(long)r * 1024];
        }

    f32x4 acc[5][2];
    #pragma unroll
    for (int t = 0; t < 8; ++t) {
        const int cb = t & 1;
        #pragma unroll
        for (int fm = 0; fm < 5; ++fm)
            #pragma unroll
            for (int fn = 0; fn < 2; ++fn)
                #pragma unroll
                for (int r = 0; r < 4; ++r)
                    acc[fm][fn][r] = b2f(x2[cb][fm][fn][r]);
        // prefetch t+1 (overlaps with MFMAs below)
        if (t < 7) {
            #pragma unroll
            for (int fm = 0; fm < 5; ++fm)
                #pragma unroll
                for (int fn = 0; fn < 2; ++fn) {
                    int col = wid * 32 + fn * 16 + (lane & 15);
                    const unsigned short* src = xih + ((i0 + fm * 16 + (lane >> 4) * 4) * 8 + (t + 1)) * 128 + col;
                    #pragma unroll
                    for (int r = 0; r < 4; ++r) x2[cb ^ 1][fm][fn][r] = src[(long)r * 1024];
                }
        }
        #pragma unroll
        for (int ks = 0; ks < 4; ++ks) {
            bf16x8 a[5], b[2];
            #pragma unroll
            for (int fm = 0; fm < 5; ++fm) {
                int row = fm * 16 + (lane & 15);
                int byte = (row * 256 + ks * 64 + (lane >> 4) * 16) ^ ((row & 7) << 4);
                a[fm] = *(const bf16x8*)((const char*)hs + byte);
            }
            #pragma unroll
            for (int fn = 0; fn < 2; ++fn) {
                int rowb = wid * 32 + fn * 16 + (lane & 15);
                int byte = (rowb * 256 + ks * 64 + (lane >> 4) * 16) ^ ((rowb & 7) << 4);
                b[fn] = *(const bf16x8*)((const char*)ws + byte);
            }
            #pragma unroll
            for (int fm = 0; fm < 5; ++fm)
                #pragma unroll
                for (int fn = 0; fn < 2; ++fn)
                    acc[fm][fn] = __builtin_amdgcn_mfma_f32_16x16x32_bf16(a[fm], b[fn], acc[fm][fn], 0, 0, 0);
        }
        __syncthreads();   // all reads of h_{t-1} done
        #pragma unroll
        for (int fm = 0; fm < 5; ++fm)
            #pragma unroll
            for (int fn = 0; fn < 2; ++fn) {
                int col = wid * 32 + fn * 16 + (lane & 15);
                #pragma unroll
                for (int r = 0; r < 4; ++r) {
                    int row = fm * 16 + (lane >> 4) * 4 + r;
                    float v = tanh_fast(acc[fm][fn][r]);
                    unsigned short hb = f2b(v);
                    int byte = (row * 256 + col * 2) ^ ((row & 7) << 4);
                    *(unsigned short*)((char*)hs + byte) = hb;
                    rout[((i0 + row) * 8 + t) * 128 + col] = hb;
                }
            }
        __syncthreads();   // h_t fully written
    }
}

// -------------- fused 3-layer MLP: 64 rows/block, 8 waves, y1/y2 in swizzled LDS ----------------
__global__ __launch_bounds__(512) void mlp_kernel(
        const unsigned short* __restrict__ A,
        const unsigned short* __restrict__ w1f, const float* __restrict__ b1,
        const unsigned short* __restrict__ w2f, const float* __restrict__ b2,
        const unsigned short* __restrict__ w3f, const float* __restrict__ b3,
        float* __restrict__ out) {
    __shared__ __align__(16) char smem[147456];   // As 16K | y1s 64K | y2s 64K
    char* As  = smem;
    char* y1s = smem + 16384;
    char* y2s = smem + 81920;
    float* red = (float*)smem;                    // phase-3 reduce: 4 bufs x 64x65 f32 (aliases As+y1s)

    const int tid = threadIdx.x, lane = tid & 63, w = tid >> 6;
    const long r0 = (long)blockIdx.x * 64;

    // stage A tile 64x128 bf16, swizzled
    #pragma unroll
    for (int p = 0; p < 2; ++p) {
        int idx = p * 512 + tid;              // 1024 int4
        int row = idx >> 4, c16 = idx & 15;
        int4 v = *(const int4*)(A + (r0 + row) * 128 + c16 * 8);
        int byte = (row * 256 + c16 * 16) ^ ((row & 7) << 4);
        *(int4*)(As + byte) = v;
    }
    __syncthreads();

    f32x4 acc[4][4];

    // ---- phase 1: y1 = relu(A @ w1^T + b1), wave w owns cols [w*64, w*64+64) ----
    #pragma unroll
    for (int fm = 0; fm < 4; ++fm)
        #pragma unroll
        for (int fn = 0; fn < 4; ++fn) acc[fm][fn] = (f32x4){0.f, 0.f, 0.f, 0.f};
    #pragma unroll
    for (int ks = 0; ks < 4; ++ks) {
        bf16x8 a[4], b[4];
        #pragma unroll
        for (int fm = 0; fm < 4; ++fm) {
            int row = fm * 16 + (lane & 15);
            a[fm] = *(const bf16x8*)(As + ((row * 256 + ks * 64 + (lane >> 4) * 16) ^ ((row & 7) << 4)));
        }
        #pragma unroll
        for (int fn = 0; fn < 4; ++fn)
            b[fn] = *(const bf16x8*)(w1f + (long)((w * 4 + fn) * 4 + ks) * 512 + lane * 8);
        #pragma unroll
        for (int fm = 0; fm < 4; ++fm)
            #pragma unroll
            for (int fn = 0; fn < 4; ++fn)
                acc[fm][fn] = __builtin_amdgcn_mfma_f32_16x16x32_bf16(a[fm], b[fn], acc[fm][fn], 0, 0, 0);
    }
    #pragma unroll
    for (int fn = 0; fn < 4; ++fn) {
        int colg = w * 64 + fn * 16 + (lane & 15);
        float bv = b1[colg];
        #pragma unroll
        for (int fm = 0; fm < 4; ++fm)
            #pragma unroll
            for (int r = 0; r < 4; ++r) {
                int row = fm * 16 + (lane >> 4) * 4 + r;
                float v = fmaxf(acc[fm][fn][r] + bv, 0.f);
                int byte = (row * 1024 + colg * 2) ^ ((row & 7) << 4);
                *(unsigned short*)(y1s + byte) = f2b(v);
            }
    }
    __syncthreads();

    // ---- phase 2: y2 = relu(y1 @ w2^T + b2) ----
    #pragma unroll
    for (int fm = 0; fm < 4; ++fm)
        #pragma unroll
        for (int fn = 0; fn < 4; ++fn) acc[fm][fn] = (f32x4){0.f, 0.f, 0.f, 0.f};
    #pragma unroll
    for (int ks = 0; ks < 16; ++ks) {
        bf16x8 a[4], b[4];
        #pragma unroll
        for (int fm = 0; fm < 4; ++fm) {
            int row = fm * 16 + (lane & 15);
            a[fm] = *(const bf16x8*)(y1s + ((row * 1024 + ks * 64 + (lane >> 4) * 16) ^ ((row & 7) << 4)));
        }
        #pragma unroll
        for (int fn = 0; fn < 4; ++fn)
            b[fn] = *(const bf16x8*)(w2f + (long)((w * 4 + fn) * 16 + ks) * 512 + lane * 8);
        #pragma unroll
        for (int fm = 0; fm < 4; ++fm)
            #pragma unroll
            for (int fn = 0; fn < 4; ++fn)
                acc[fm][fn] = __builtin_amdgcn_mfma_f32_16x16x32_bf16(a[fm], b[fn], acc[fm][fn], 0, 0, 0);
    }
    #pragma unroll
    for (int fn = 0; fn < 4; ++fn) {
        int colg = w * 64 + fn * 16 + (lane & 15);
        float bv = b2[colg];
        #pragma unroll
        for (int fm = 0; fm < 4; ++fm)
            #pragma unroll
            for (int r = 0; r < 4; ++r) {
                int row = fm * 16 + (lane >> 4) * 4 + r;
                float v = fmaxf(acc[fm][fn][r] + bv, 0.f);
                int byte = (row * 1024 + colg * 2) ^ ((row & 7) << 4);
                *(unsigned short*)(y2s + byte) = f2b(v);
            }
    }
    __syncthreads();

    // ---- phase 3: out = y2 @ w3^T + b3, k-split across waves (64 k each), tree-reduce ----
    #pragma unroll
    for (int fm = 0; fm < 4; ++fm)
        #pragma unroll
        for (int fn = 0; fn < 4; ++fn) acc[fm][fn] = (f32x4){0.f, 0.f, 0.f, 0.f};
    #pragma unroll
    for (int ksl = 0; ksl < 2; ++ksl) {
        int ks = w * 2 + ksl;
        bf16x8 a[4], b[4];
        #pragma unroll
        for (int fm = 0; fm < 4; ++fm) {
            int row = fm * 16 + (lane & 15);
            a[fm] = *(const bf16x8*)(y2s + ((row * 1024 + ks * 64 + (lane >> 4) * 16) ^ ((row & 7) << 4)));
        }
        #pragma unroll
        for (int fn = 0; fn < 4; ++fn)
            b[fn] = *(const bf16x8*)(w3f + (long)(fn * 16 + ks) * 512 + lane * 8);
        #pragma unroll
        for (int fm = 0; fm < 4; ++fm)
            #pragma unroll
            for (int fn = 0; fn < 4; ++fn)
                acc[fm][fn] = __builtin_amdgcn_mfma_f32_16x16x32_bf16(a[fm], b[fn], acc[fm][fn], 0, 0, 0);
    }
    // tree reduction over 8 wave-partials (bufs stride 65 f32/row to dodge bank conflicts)
    {
        // step A: waves 4-7 dump, waves 0-3 add
        if (w >= 4) {
            float* rb = red + (w - 4) * 4160;
            #pragma unroll
            for (int fm = 0; fm < 4; ++fm)
                #pragma unroll
                for (int fn = 0; fn < 4; ++fn)
                    #pragma unroll
                    for (int r = 0; r < 4; ++r)
                        rb[(fm * 16 + (lane >> 4) * 4 + r) * 65 + fn * 16 + (lane & 15)] = acc[fm][fn][r];
        }
        __syncthreads();
        if (w < 4) {
            float* rb = red + w * 4160;
            #pragma unroll
            for (int fm = 0; fm < 4; ++fm)
                #pragma unroll
                for (int fn = 0; fn < 4; ++fn)
                    #pragma unroll
                    for (int r = 0; r < 4; ++r)
                        acc[fm][fn][r] += rb[(fm * 16 + (lane >> 4) * 4 + r) * 65 + fn * 16 + (lane & 15)];
        }
        __syncthreads();
        // step B: waves 2-3 dump, waves 0-1 add
        if (w == 2 || w == 3) {
            float* rb = red + (w - 2) * 4160;
            #pragma unroll
            for (int fm = 0; fm < 4; ++fm)
                #pragma unroll
                for (int fn = 0; fn < 4; ++fn)
                    #pragma unroll
                    for (int r = 0; r < 4; ++r)
                        rb[(fm * 16 + (lane >> 4) * 4 + r) * 65 + fn * 16 + (lane & 15)] = acc[fm][fn][r];
        }
        __syncthreads();
        if (w < 2) {
            float* rb = red + w * 4160;
            #pragma unroll
            for (int fm = 0; fm < 4; ++fm)
                #pragma unroll
                for (int fn = 0; fn < 4; ++fn)
                    #pragma unroll
                    for (int r = 0; r < 4; ++r)
                        acc[fm][fn][r] += rb[(fm * 16 + (lane >> 4) * 4 + r) * 65 + fn * 16 + (lane & 15)];
        }
        __syncthreads();
        // step C: wave 1 dumps, wave 0 adds + stores
        if (w == 1) {
            float* rb = red;
            #pragma unroll
            for (int fm = 0; fm < 4; ++fm)
                #pragma unroll
                for (int fn = 0; fn < 4; ++fn)
                    #pragma unroll
                    for (int r = 0; r < 4; ++r)
                        rb[(fm * 16 + (lane >> 4) * 4 + r) * 65 + fn * 16 + (lane & 15)] = acc[fm][fn][r];
        }
        __syncthreads();
        if (w == 0) {
            float* rb = red;
            #pragma unroll
            for (int fm = 0; fm < 4; ++fm)
                #pragma unroll
                for (int fn = 0; fn < 4; ++fn) {
                    int col = fn * 16 + (lane & 15);
                    float bv = b3[col];
                    #pragma unroll
                    for (int r = 0; r < 4; ++r) {
                        int row = fm * 16 + (lane >> 4) * 4 + r;
                        float v = acc[fm][fn][r] + rb[row * 65 + col] + bv;
                        long vr = r0 + row;   // flat M row = v*8 + t
                        out[((vr >> 3) * 10 + (vr & 7)) * 64 + col] = v;
                    }
                }
        }
    }
}

extern "C" void kernel_launch(void* const* d_in, const int* in_sizes, int n_in,
                              void* d_out, int out_size, void* d_ws, size_t ws_size,
                              hipStream_t stream) {
    const float* x     = (const float*)d_in[0];
    const int*   ei    = (const int*)  d_in[1];
    const float* ew    = (const float*)d_in[2];
    const float* gcn_w = (const float*)d_in[3];
    const float* gcn_b = (const float*)d_in[4];
    const float* w_ih  = (const float*)d_in[5];
    const float* w_hh  = (const float*)d_in[6];
    const float* b_ih  = (const float*)d_in[7];
    const float* b_hh  = (const float*)d_in[8];
    const float* w1    = (const float*)d_in[9];
    const float* b1    = (const float*)d_in[10];
    const float* w2    = (const float*)d_in[11];
    const float* b2    = (const float*)d_in[12];
    const float* w3    = (const float*)d_in[13];
    const float* b3    = (const float*)d_in[14];

    // ---- workspace layout (peak ~109 MiB, well under proven 122 MiB) ----
    // [0, 20.5M):  xlt bf16 [N][16][64]  -> dead after aggregate
    // [0, 41.0M):  rnno bf16 [160000][128] (after aggregate)
    // [41.94M, 62.43M): gc bf16 [160000][64]  -> dead after GEMM-ih
    // [62.92M, 103.88M): xih bf16 [160000][128] -> dead after RNN
    // [104.86M, ~105.6M): w1f/w2f/w3f bf16 frag-major
    // [106.95M, ...): small graph buffers (~1.7 MB)
    char* ws = (char*)d_ws;
    unsigned short* xlt  = (unsigned short*)ws;
    unsigned short* rnno = (unsigned short*)ws;
    unsigned short* gc   = (unsigned short*)(ws + 41943040L);
    unsigned short* xih  = (unsigned short*)(ws + 62914560L);
    unsigned short* w1f  = (unsigned short*)(ws + 104857600L);   // 128 KB
    unsigned short* w2f  = (unsigned short*)(ws + 104988672L);   // 512 KB
    unsigned short* w3f  = (unsigned short*)(ws + 105512960L);   // 64 KB
    char* sm = ws + 106954752L;
    float* deg    = (float*)(sm);
    float* dinv   = (float*)(sm + (64 << 10));
    int*   cnt    = (int*)  (sm + (128 << 10));
    int*   offs   = (int*)  (sm + (192 << 10));
    int*   cursor = (int*)  (sm + (256 << 10));
    int*   erow   = (int*)  (sm + (320 << 10));
    float* enorm  = (float*)(sm + (1 << 20));

    hipMemsetAsync(d_out, 0, (size_t)out_size * sizeof(float), stream);  // prediction slots stay 0

    init_kernel<<<40, 256, 0, stream>>>(deg, cnt);
    deg_add_kernel<<<625, 256, 0, stream>>>(ei, ew, deg, cnt);
    dinv_kernel<<<40, 256, 0, stream>>>(deg, dinv);
    scan_kernel<<<1, 1024, 0, stream>>>(cnt, offs, cursor);
    fill_kernel<<<625, 256, 0, stream>>>(ei, ew, dinv, cursor, erow, enorm);

    wconv_kernel<4, 128><<<32, 256, 0, stream>>>(w1, w1f);     // NF=32
    wconv_kernel<16, 512><<<128, 256, 0, stream>>>(w2, w2f);   // NF=32
    wconv_kernel<16, 512><<<16, 256, 0, stream>>>(w3, w3f);    // NF=4

    // xl^T[n][g][f] = x[g,n,:] . gcn_w[f,:]  (bf16 out, scattered)
    gemm_kernel<64, 64, 64, true, 0, false><<<dim3(1250, 1), 256, 0, stream>>>(x, gcn_w, nullptr, nullptr, xlt);
    aggregate_kernel<<<5000, 256, 0, stream>>>(xlt, erow, enorm, offs, dinv, gcn_b, gc);
    // xih[v][h] = gc[v,:] . w_ih[h,:] + b_ih + b_hh  (bf16 out)
    gemm_kernel<128, 128, 64, false, 2, false><<<dim3(1250, 1), 256, 0, stream>>>(gc, w_ih, b_ih, b_hh, xih);
    rnn_kernel<<<250, 256, 0, stream>>>(xih, w_hh, rnno);
    mlp_kernel<<<2500, 512, 0, stream>>>(rnno, w1f, b1, w2f, b2, w3f, b3, (float*)d_out);
}

// Round 7
// 402.185 us; speedup vs baseline: 1.7764x; 1.1246x over previous
//
#include <hip/hip_runtime.h>
#include <hip/hip_bf16.h>

#define N_NODES 10000
#define E_EDGES 160000

typedef __attribute__((ext_vector_type(8))) short bf16x8;
typedef __attribute__((ext_vector_type(4))) float f32x4;

__device__ __forceinline__ unsigned short f2b(float f) {
    unsigned int u = __float_as_uint(f);
    u = (u + 0x7fffu + ((u >> 16) & 1u)) >> 16;
    return (unsigned short)u;
}

__device__ __forceinline__ float b2f(unsigned short u) {
    return __uint_as_float(((unsigned int)u) << 16);
}

__device__ __forceinline__ float tanh_fast(float x) {
    float ax = fabsf(x);
    float e = __expf(-2.f * ax);
    float r = (1.f - e) / (1.f + e);
    return copysignf(r, x);
}

// ---------------- small GCN-prep kernels ----------------
__global__ void init_kernel(float* deg, int* cnt) {
    int i = blockIdx.x * 256 + threadIdx.x;
    if (i < N_NODES) { deg[i] = 1.0f; cnt[i] = 0; }   // 1.0 = self-loop weight
}

__global__ void deg_add_kernel(const int* __restrict__ ei, const float* __restrict__ ew,
                               float* deg, int* cnt) {
    int e = blockIdx.x * 256 + threadIdx.x;
    if (e < E_EDGES) {
        int c = ei[E_EDGES + e];
        atomicAdd(&deg[c], ew[e]);
        atomicAdd(&cnt[c], 1);
    }
}

__global__ void dinv_kernel(const float* __restrict__ deg, float* dinv) {
    int i = blockIdx.x * 256 + threadIdx.x;
    if (i < N_NODES) { float d = deg[i]; dinv[i] = d > 0.f ? rsqrtf(d) : 0.f; }
}

// exclusive prefix sum of cnt[N] -> offs[N+1], cursor[N]
__global__ void scan_kernel(const int* __restrict__ cnt, int* offs, int* cursor) {
    __shared__ int tsum[1024];
    int t = threadIdx.x;
    int base = t * 10;
    int loc[10];
    int s = 0;
    #pragma unroll
    for (int j = 0; j < 10; ++j) {
        int i = base + j;
        int v = (i < N_NODES) ? cnt[i] : 0;
        loc[j] = s; s += v;
    }
    tsum[t] = s;
    __syncthreads();
    for (int d = 1; d < 1024; d <<= 1) {
        int v = (t >= d) ? tsum[t - d] : 0;
        __syncthreads();
        tsum[t] += v;
        __syncthreads();
    }
    int pre = tsum[t] - s;   // exclusive
    #pragma unroll
    for (int j = 0; j < 10; ++j) {
        int i = base + j;
        if (i < N_NODES) { offs[i] = pre + loc[j]; cursor[i] = pre + loc[j]; }
    }
    if (t == 1023) offs[N_NODES] = tsum[1023];
}

__global__ void fill_kernel(const int* __restrict__ ei, const float* __restrict__ ew,
                            const float* __restrict__ dinv, int* cursor,
                            int* erow, float* enorm) {
    int e = blockIdx.x * 256 + threadIdx.x;
    if (e < E_EDGES) {
        int r = ei[e], c = ei[E_EDGES + e];
        float nm = dinv[r] * ew[e] * dinv[c];
        int pos = atomicAdd(&cursor[c], 1);
        erow[pos] = r; enorm[pos] = nm;
    }
}

// ---- weight -> bf16 MFMA-fragment-major layout: frag(nf,ks) = 1KB, lane-major ----
template<int KS, int K>
__global__ void wconv_kernel(const float* __restrict__ w, unsigned short* __restrict__ o) {
    int idx = blockIdx.x * 256 + threadIdx.x;   // frag*64 + lane
    int lane = idx & 63, frag = idx >> 6;
    int nf = frag / KS, ks = frag % KS;
    const float* src = w + (nf * 16 + (lane & 15)) * K + ks * 32 + (lane >> 4) * 8;
    unsigned short* dst = o + frag * 512 + lane * 8;
    float4 v0 = *(const float4*)src;
    float4 v1 = *(const float4*)(src + 4);
    ushort4 h0; h0.x = f2b(v0.x); h0.y = f2b(v0.y); h0.z = f2b(v0.z); h0.w = f2b(v0.w);
    ushort4 h1; h1.x = f2b(v1.x); h1.y = f2b(v1.y); h1.z = f2b(v1.z); h1.w = f2b(v1.w);
    *(ushort4*)dst = h0;
    *(ushort4*)(dst + 4) = h1;
}

// -------------- CSR gather-aggregate: 2 waves per target node (8 graphs each) ----------------
// xlt layout: [N][G=16][64] bf16. gc layout: [G][N][64] bf16 (== seq flat rows)
__global__ __launch_bounds__(256) void aggregate_kernel(
        const unsigned short* __restrict__ xlt, const int* __restrict__ erow,
        const float* __restrict__ enorm, const int* __restrict__ offs,
        const float* __restrict__ dinv, const float* __restrict__ gcn_b,
        unsigned short* __restrict__ gc) {
    int gwid = (blockIdx.x * 256 + threadIdx.x) >> 6;   // 20000 waves
    int c = gwid >> 1;
    int gh = (gwid & 1) * 8;
    int lane = threadIdx.x & 63;
    if (c >= N_NODES) return;
    float acc[8];
    float d = dinv[c];
    float wself = d * d;
    const unsigned short* xr = xlt + (long)c * 1024 + gh * 64;
    #pragma unroll
    for (int g = 0; g < 8; ++g) acc[g] = b2f(xr[g * 64 + lane]) * wself;
    int e0 = offs[c], e1 = offs[c + 1];
    for (int e = e0; e < e1; ++e) {
        int r = erow[e];
        float nm = enorm[e];
        const unsigned short* xs = xlt + (long)r * 1024 + gh * 64;
        #pragma unroll
        for (int g = 0; g < 8; ++g) acc[g] += b2f(xs[g * 64 + lane]) * nm;
    }
    float bb = gcn_b[lane];
    #pragma unroll
    for (int g = 0; g < 8; ++g)
        gc[(long)(gh + g) * 640000 + (long)c * 64 + lane] = f2b(acc[g] + bb);
}

// -------------- generic bf16-MFMA GEMM: C[m,n] = A[m,:K] . W[n,:K] + bias ----------------
// BM=128, BK=64, 4 waves (2x2). EPI: 0=xlt scatter bf16, 2=bf16(+relu)
template<int NTOT, int BN, int KTOT, bool AF32, int EPI, bool RELU>
__global__ __launch_bounds__(256) void gemm_kernel(
        const void* __restrict__ Aptr, const float* __restrict__ Wp,
        const float* __restrict__ bias0, const float* __restrict__ bias1,
        void* __restrict__ outp) {
    constexpr int WN = BN / 2;
    constexpr int FN = WN / 16;
    __shared__ __align__(16) unsigned short As[128 * 72];
    __shared__ __align__(16) unsigned short Bs[BN * 72];
    const int tid = threadIdx.x;
    const int lane = tid & 63;
    const int wid = tid >> 6;
    const int wm = wid >> 1, wn = wid & 1;
    const long m0 = (long)blockIdx.x * 128;
    const int n0 = blockIdx.y * BN;

    f32x4 acc[4][FN];
    #pragma unroll
    for (int a = 0; a < 4; ++a)
        #pragma unroll
        for (int b = 0; b < FN; ++b)
            acc[a][b] = (f32x4){0.f, 0.f, 0.f, 0.f};

    for (int kt = 0; kt < KTOT / 64; ++kt) {
        if (AF32) {
            const float* Ag = (const float*)Aptr;
            #pragma unroll
            for (int p = 0; p < 8; ++p) {
                int idx = p * 256 + tid;
                int r = idx >> 4, c4 = idx & 15;
                float4 v = *(const float4*)(Ag + (m0 + r) * KTOT + kt * 64 + c4 * 4);
                ushort4 h; h.x = f2b(v.x); h.y = f2b(v.y); h.z = f2b(v.z); h.w = f2b(v.w);
                *(ushort4*)&As[r * 72 + c4 * 4] = h;
            }
        } else {
            const unsigned short* Ag = (const unsigned short*)Aptr;
            #pragma unroll
            for (int p = 0; p < 4; ++p) {
                int idx = p * 256 + tid;
                int r = idx >> 3, c8 = idx & 7;
                *(int4*)&As[r * 72 + c8 * 8] = *(const int4*)(Ag + (m0 + r) * KTOT + kt * 64 + c8 * 8);
            }
        }
        #pragma unroll
        for (int p = 0; p < BN / 16; ++p) {
            int idx = p * 256 + tid;
            int r = idx >> 4, c4 = idx & 15;
            float4 v = *(const float4*)(Wp + (long)(n0 + r) * KTOT + kt * 64 + c4 * 4);
            ushort4 h; h.x = f2b(v.x); h.y = f2b(v.y); h.z = f2b(v.z); h.w = f2b(v.w);
            *(ushort4*)&Bs[r * 72 + c4 * 4] = h;
        }
        __syncthreads();
        #pragma unroll
        for (int ks = 0; ks < 2; ++ks) {
            bf16x8 a[4], b[FN];
            #pragma unroll
            for (int fm = 0; fm < 4; ++fm)
                a[fm] = *(const bf16x8*)&As[(wm * 64 + fm * 16 + (lane & 15)) * 72 + ks * 32 + (lane >> 4) * 8];
            #pragma unroll
            for (int fn = 0; fn < FN; ++fn)
                b[fn] = *(const bf16x8*)&Bs[(wn * WN + fn * 16 + (lane & 15)) * 72 + ks * 32 + (lane >> 4) * 8];
            #pragma unroll
            for (int fm = 0; fm < 4; ++fm)
                #pragma unroll
                for (int fn = 0; fn < FN; ++fn)
                    acc[fm][fn] = __builtin_amdgcn_mfma_f32_16x16x32_bf16(a[fm], b[fn], acc[fm][fn], 0, 0, 0);
        }
        __syncthreads();
    }

    #pragma unroll
    for (int fm = 0; fm < 4; ++fm) {
        #pragma unroll
        for (int fn = 0; fn < FN; ++fn) {
            const int colg = n0 + wn * WN + fn * 16 + (lane & 15);
            float bv = 0.f;
            if (bias0) bv += bias0[colg];
            if (bias1) bv += bias1[colg];
            #pragma unroll
            for (int r = 0; r < 4; ++r) {
                int row = (int)m0 + wm * 64 + fm * 16 + (lane >> 4) * 4 + r;
                float v = acc[fm][fn][r] + bv;
                if (RELU) v = fmaxf(v, 0.f);
                if (EPI == 0) {
                    ((unsigned short*)outp)[(long)(row % N_NODES) * 1024 + (long)(row / N_NODES) * 64 + colg] = f2b(v);
                } else {
                    ((unsigned short*)outp)[(long)row * NTOT + colg] = f2b(v);
                }
            }
        }
    }
}

// -------------- RNN recurrence: 32 seqs/block (625 blocks), 8 steps, w_hh in LDS ----------------
// 40 KiB LDS -> ~4 blocks/CU; xih prefetch ping-pong (t unrolled -> static indexing)
__global__ __launch_bounds__(256) void rnn_kernel(const unsigned short* __restrict__ xih,
                                                  const float* __restrict__ whh,
                                                  unsigned short* __restrict__ rout) {
    __shared__ __align__(16) unsigned short hs[32 * 128];    // 8 KB
    __shared__ __align__(16) unsigned short ws[128 * 128];   // 32 KB
    const int tid = threadIdx.x, lane = tid & 63, wid = tid >> 6;  // 4 waves: col split of 32
    const long i0 = (long)blockIdx.x * 32;

    // stage w_hh -> bf16, XOR-swizzled rows (byte ^= (row&7)<<4)
    #pragma unroll
    for (int p = 0; p < 16; ++p) {
        int idx = p * 256 + tid;
        int n = idx >> 5, k4 = (idx & 31) * 4;
        float4 v = *(const float4*)(whh + n * 128 + k4);
        ushort4 h; h.x = f2b(v.x); h.y = f2b(v.y); h.z = f2b(v.z); h.w = f2b(v.w);
        int byte = (n * 256 + k4 * 2) ^ ((n & 7) << 4);
        *(ushort4*)((char*)ws + byte) = h;
    }
    int4 z = make_int4(0, 0, 0, 0);
    #pragma unroll
    for (int p = 0; p < 2; ++p) ((int4*)hs)[p * 256 + tid] = z;   // 8192 B
    __syncthreads();

    unsigned short x2[2][2][2][4];
    // preload t=0
    #pragma unroll
    for (int fm = 0; fm < 2; ++fm)
        #pragma unroll
        for (int fn = 0; fn < 2; ++fn) {
            int col = wid * 32 + fn * 16 + (lane & 15);
            const unsigned short* src = xih + ((i0 + fm * 16 + (lane >> 4) * 4) * 8 + 0) * 128 + col;
            #pragma unroll
            for (int r = 0; r < 4; ++r) x2[0][fm][fn][r] = src[(long)r * 1024];
        }

    f32x4 acc[2][2];
    #pragma unroll
    for (int t = 0; t < 8; ++t) {
        const int cb = t & 1;
        #pragma unroll
        for (int fm = 0; fm < 2; ++fm)
            #pragma unroll
            for (int fn = 0; fn < 2; ++fn)
                #pragma unroll
                for (int r = 0; r < 4; ++r)
                    acc[fm][fn][r] = b2f(x2[cb][fm][fn][r]);
        // prefetch t+1 (overlaps with MFMAs below)
        if (t < 7) {
            #pragma unroll
            for (int fm = 0; fm < 2; ++fm)
                #pragma unroll
                for (int fn = 0; fn < 2; ++fn) {
                    int col = wid * 32 + fn * 16 + (lane & 15);
                    const unsigned short* src = xih + ((i0 + fm * 16 + (lane >> 4) * 4) * 8 + (t + 1)) * 128 + col;
                    #pragma unroll
                    for (int r = 0; r < 4; ++r) x2[cb ^ 1][fm][fn][r] = src[(long)r * 1024];
                }
        }
        #pragma unroll
        for (int ks = 0; ks < 4; ++ks) {
            bf16x8 a[2], b[2];
            #pragma unroll
            for (int fm = 0; fm < 2; ++fm) {
                int row = fm * 16 + (lane & 15);
                int byte = (row * 256 + ks * 64 + (lane >> 4) * 16) ^ ((row & 7) << 4);
                a[fm] = *(const bf16x8*)((const char*)hs + byte);
            }
            #pragma unroll
            for (int fn = 0; fn < 2; ++fn) {
                int rowb = wid * 32 + fn * 16 + (lane & 15);
                int byte = (rowb * 256 + ks * 64 + (lane >> 4) * 16) ^ ((rowb & 7) << 4);
                b[fn] = *(const bf16x8*)((const char*)ws + byte);
            }
            #pragma unroll
            for (int fm = 0; fm < 2; ++fm)
                #pragma unroll
                for (int fn = 0; fn < 2; ++fn)
                    acc[fm][fn] = __builtin_amdgcn_mfma_f32_16x16x32_bf16(a[fm], b[fn], acc[fm][fn], 0, 0, 0);
        }
        __syncthreads();   // all reads of h_{t-1} done
        #pragma unroll
        for (int fm = 0; fm < 2; ++fm)
            #pragma unroll
            for (int fn = 0; fn < 2; ++fn) {
                int col = wid * 32 + fn * 16 + (lane & 15);
                #pragma unroll
                for (int r = 0; r < 4; ++r) {
                    int row = fm * 16 + (lane >> 4) * 4 + r;
                    float v = tanh_fast(acc[fm][fn][r]);
                    unsigned short hb = f2b(v);
                    int byte = (row * 256 + col * 2) ^ ((row & 7) << 4);
                    *(unsigned short*)((char*)hs + byte) = hb;
                    rout[((i0 + row) * 8 + t) * 128 + col] = hb;
                }
            }
        __syncthreads();   // h_t fully written
    }
}

// -------------- fused 3-layer MLP: 64 rows/block, 8 waves, 80 KiB LDS (2 blocks/CU) ----------------
// phase1: y1 -> ys; phase2: reads ys, then (barrier) y2 overwrites ys; phase3: fn x k-half split,
// single pair-exchange reduce. Swizzle (row&15)<<4 is bijective in the 1024B/256B row stripes.
__global__ __launch_bounds__(512) void mlp_kernel(
        const unsigned short* __restrict__ A,
        const unsigned short* __restrict__ w1f, const float* __restrict__ b1,
        const unsigned short* __restrict__ w2f, const float* __restrict__ b2,
        const unsigned short* __restrict__ w3f, const float* __restrict__ b3,
        float* __restrict__ out) {
    __shared__ __align__(16) char smem[81920];   // As 16K | ys 64K
    char* As = smem;
    char* ys = smem + 16384;

    const int tid = threadIdx.x, lane = tid & 63, w = tid >> 6;
    const long r0 = (long)blockIdx.x * 64;

    // stage A tile 64x128 bf16, swizzled
    #pragma unroll
    for (int p = 0; p < 2; ++p) {
        int idx = p * 512 + tid;              // 1024 int4
        int row = idx >> 4, c16 = idx & 15;
        int4 v = *(const int4*)(A + (r0 + row) * 128 + c16 * 8);
        int byte = (row * 256 + c16 * 16) ^ ((row & 15) << 4);
        *(int4*)(As + byte) = v;
    }
    __syncthreads();

    f32x4 acc[4][4];

    // ---- phase 1: y1 = relu(A @ w1^T + b1), wave w owns cols [w*64, w*64+64) ----
    #pragma unroll
    for (int fm = 0; fm < 4; ++fm)
        #pragma unroll
        for (int fn = 0; fn < 4; ++fn) acc[fm][fn] = (f32x4){0.f, 0.f, 0.f, 0.f};
    #pragma unroll
    for (int ks = 0; ks < 4; ++ks) {
        bf16x8 a[4], b[4];
        #pragma unroll
        for (int fm = 0; fm < 4; ++fm) {
            int row = fm * 16 + (lane & 15);
            a[fm] = *(const bf16x8*)(As + ((row * 256 + ks * 64 + (lane >> 4) * 16) ^ ((row & 15) << 4)));
        }
        #pragma unroll
        for (int fn = 0; fn < 4; ++fn)
            b[fn] = *(const bf16x8*)(w1f + (long)((w * 4 + fn) * 4 + ks) * 512 + lane * 8);
        #pragma unroll
        for (int fm = 0; fm < 4; ++fm)
            #pragma unroll
            for (int fn = 0; fn < 4; ++fn)
                acc[fm][fn] = __builtin_amdgcn_mfma_f32_16x16x32_bf16(a[fm], b[fn], acc[fm][fn], 0, 0, 0);
    }
    #pragma unroll
    for (int fn = 0; fn < 4; ++fn) {
        int colg = w * 64 + fn * 16 + (lane & 15);
        float bv = b1[colg];
        #pragma unroll
        for (int fm = 0; fm < 4; ++fm)
            #pragma unroll
            for (int r = 0; r < 4; ++r) {
                int row = fm * 16 + (lane >> 4) * 4 + r;
                float v = fmaxf(acc[fm][fn][r] + bv, 0.f);
                int byte = (row * 1024 + colg * 2) ^ ((row & 15) << 4);
                *(unsigned short*)(ys + byte) = f2b(v);
            }
    }
    __syncthreads();

    // ---- phase 2: y2 = relu(y1 @ w2^T + b2), accumulate in regs ----
    #pragma unroll
    for (int fm = 0; fm < 4; ++fm)
        #pragma unroll
        for (int fn = 0; fn < 4; ++fn) acc[fm][fn] = (f32x4){0.f, 0.f, 0.f, 0.f};
    #pragma unroll
    for (int ks = 0; ks < 16; ++ks) {
        bf16x8 a[4], b[4];
        #pragma unroll
        for (int fm = 0; fm < 4; ++fm) {
            int row = fm * 16 + (lane & 15);
            a[fm] = *(const bf16x8*)(ys + ((row * 1024 + ks * 64 + (lane >> 4) * 16) ^ ((row & 15) << 4)));
        }
        #pragma unroll
        for (int fn = 0; fn < 4; ++fn)
            b[fn] = *(const bf16x8*)(w2f + (long)((w * 4 + fn) * 16 + ks) * 512 + lane * 8);
        #pragma unroll
        for (int fm = 0; fm < 4; ++fm)
            #pragma unroll
            for (int fn = 0; fn < 4; ++fn)
                acc[fm][fn] = __builtin_amdgcn_mfma_f32_16x16x32_bf16(a[fm], b[fn], acc[fm][fn], 0, 0, 0);
    }
    __syncthreads();   // all y1 reads complete -> safe to overwrite ys with y2
    #pragma unroll
    for (int fn = 0; fn < 4; ++fn) {
        int colg = w * 64 + fn * 16 + (lane & 15);
        float bv = b2[colg];
        #pragma unroll
        for (int fm = 0; fm < 4; ++fm)
            #pragma unroll
            for (int r = 0; r < 4; ++r) {
                int row = fm * 16 + (lane >> 4) * 4 + r;
                float v = fmaxf(acc[fm][fn][r] + bv, 0.f);
                int byte = (row * 1024 + colg * 2) ^ ((row & 15) << 4);
                *(unsigned short*)(ys + byte) = f2b(v);
            }
    }
    __syncthreads();   // y2 visible

    // ---- phase 3: out = y2 @ w3^T + b3; wave w: fn = w&3, k-half = w>>2; pair reduce ----
    const int fn3 = w & 3, kh = w >> 2;
    f32x4 a3[4];
    #pragma unroll
    for (int fm = 0; fm < 4; ++fm) a3[fm] = (f32x4){0.f, 0.f, 0.f, 0.f};
    #pragma unroll
    for (int ksl = 0; ksl < 8; ++ksl) {
        int ks = kh * 8 + ksl;
        bf16x8 bfrag = *(const bf16x8*)(w3f + (long)(fn3 * 16 + ks) * 512 + lane * 8);
        #pragma unroll
        for (int fm = 0; fm < 4; ++fm) {
            int row = fm * 16 + (lane & 15);
            bf16x8 afrag = *(const bf16x8*)(ys + ((row * 1024 + ks * 64 + (lane >> 4) * 16) ^ ((row & 15) << 4)));
            a3[fm] = __builtin_amdgcn_mfma_f32_16x16x32_bf16(afrag, bfrag, a3[fm], 0, 0, 0);
        }
    }
    __syncthreads();   // all y2 reads complete -> ys reusable as f32 reduce scratch
    if (w >= 4) {      // k-half 1 dumps partials: 4 bufs x (64 rows x 17 f32)
        float* rb = (float*)(ys) + (w - 4) * 1104;
        #pragma unroll
        for (int fm = 0; fm < 4; ++fm)
            #pragma unroll
            for (int r = 0; r < 4; ++r)
                rb[(fm * 16 + (lane >> 4) * 4 + r) * 17 + (lane & 15)] = a3[fm][r];
    }
    __syncthreads();
    if (w < 4) {       // k-half 0 adds partner's partial, writes out
        float* rb = (float*)(ys) + w * 1104;
        float bv = b3[fn3 * 16 + (lane & 15)];
        #pragma unroll
        for (int fm = 0; fm < 4; ++fm)
            #pragma unroll
            for (int r = 0; r < 4; ++r) {
                int row = fm * 16 + (lane >> 4) * 4 + r;
                float v = a3[fm][r] + rb[row * 17 + (lane & 15)] + bv;
                long vr = r0 + row;   // flat M row = v*8 + t
                out[((vr >> 3) * 10 + (vr & 7)) * 64 + fn3 * 16 + (lane & 15)] = v;
            }
    }
}

extern "C" void kernel_launch(void* const* d_in, const int* in_sizes, int n_in,
                              void* d_out, int out_size, void* d_ws, size_t ws_size,
                              hipStream_t stream) {
    const float* x     = (const float*)d_in[0];
    const int*   ei    = (const int*)  d_in[1];
    const float* ew    = (const float*)d_in[2];
    const float* gcn_w = (const float*)d_in[3];
    const float* gcn_b = (const float*)d_in[4];
    const float* w_ih  = (const float*)d_in[5];
    const float* w_hh  = (const float*)d_in[6];
    const float* b_ih  = (const float*)d_in[7];
    const float* b_hh  = (const float*)d_in[8];
    const float* w1    = (const float*)d_in[9];
    const float* b1    = (const float*)d_in[10];
    const float* w2    = (const float*)d_in[11];
    const float* b2    = (const float*)d_in[12];
    const float* w3    = (const float*)d_in[13];
    const float* b3    = (const float*)d_in[14];

    // ---- workspace layout (peak ~107 MiB) ----
    char* ws = (char*)d_ws;
    unsigned short* xlt  = (unsigned short*)ws;                  // [N][16][64] bf16, dead after aggregate
    unsigned short* rnno = (unsigned short*)ws;                  // [160000][128] bf16
    unsigned short* gc   = (unsigned short*)(ws + 41943040L);    // [160000][64] bf16
    unsigned short* xih  = (unsigned short*)(ws + 62914560L);    // [160000][128] bf16
    unsigned short* w1f  = (unsigned short*)(ws + 104857600L);   // 128 KB
    unsigned short* w2f  = (unsigned short*)(ws + 104988672L);   // 512 KB
    unsigned short* w3f  = (unsigned short*)(ws + 105512960L);   // 64 KB
    char* sm = ws + 106954752L;
    float* deg    = (float*)(sm);
    float* dinv   = (float*)(sm + (64 << 10));
    int*   cnt    = (int*)  (sm + (128 << 10));
    int*   offs   = (int*)  (sm + (192 << 10));
    int*   cursor = (int*)  (sm + (256 << 10));
    int*   erow   = (int*)  (sm + (320 << 10));
    float* enorm  = (float*)(sm + (1 << 20));

    hipMemsetAsync(d_out, 0, (size_t)out_size * sizeof(float), stream);  // prediction slots stay 0

    init_kernel<<<40, 256, 0, stream>>>(deg, cnt);
    deg_add_kernel<<<625, 256, 0, stream>>>(ei, ew, deg, cnt);
    dinv_kernel<<<40, 256, 0, stream>>>(deg, dinv);
    scan_kernel<<<1, 1024, 0, stream>>>(cnt, offs, cursor);
    fill_kernel<<<625, 256, 0, stream>>>(ei, ew, dinv, cursor, erow, enorm);

    wconv_kernel<4, 128><<<32, 256, 0, stream>>>(w1, w1f);     // NF=32
    wconv_kernel<16, 512><<<128, 256, 0, stream>>>(w2, w2f);   // NF=32
    wconv_kernel<16, 512><<<16, 256, 0, stream>>>(w3, w3f);    // NF=4

    // xl^T[n][g][f] = x[g,n,:] . gcn_w[f,:]  (bf16 out, scattered)
    gemm_kernel<64, 64, 64, true, 0, false><<<dim3(1250, 1), 256, 0, stream>>>(x, gcn_w, nullptr, nullptr, xlt);
    aggregate_kernel<<<5000, 256, 0, stream>>>(xlt, erow, enorm, offs, dinv, gcn_b, gc);
    // xih[v][h] = gc[v,:] . w_ih[h,:] + b_ih + b_hh  (bf16 out)
    gemm_kernel<128, 128, 64, false, 2, false><<<dim3(1250, 1), 256, 0, stream>>>(gc, w_ih, b_ih, b_hh, xih);
    rnn_kernel<<<625, 256, 0, stream>>>(xih, w_hh, rnno);
    mlp_kernel<<<2500, 512, 0, stream>>>(rnno, w1f, b1, w2f, b2, w3f, b3, (float*)d_out);
}